// Round 8
// baseline (489.155 us; speedup 1.0000x reference)
//
#include <hip/hip_runtime.h>
#include <math.h>

#define NB 8
#define NC 128
#define NT 4096
#define NF 2049
#define FP 2176   // padded F = 17*128
#define LDP 72    // LDS row pitch for non-async GEMMs (144 B)

typedef __bf16 bf16;
typedef __bf16 bf16x2 __attribute__((ext_vector_type(2)));
typedef __bf16 bf16x8 __attribute__((ext_vector_type(8)));
typedef float f32x4 __attribute__((ext_vector_type(4)));
typedef unsigned int uint32x4 __attribute__((ext_vector_type(4)));

// async global->LDS, 16 B per lane; lds dest must be wave-uniform base
__device__ __forceinline__ void async16(const bf16* g, bf16* l) {
    __builtin_amdgcn_global_load_lds(
        (const __attribute__((address_space(1))) void*)g,
        (__attribute__((address_space(3))) void*)l, 16, 0, 0);
}

// (Kr,-Ki) interleaved fragment -> (Ki,Kr): per dword swap halves, negate low
__device__ __forceinline__ bf16x8 derive_b2(bf16x8 v) {
    uint32x4 u = __builtin_bit_cast(uint32x4, v);
#pragma unroll
    for (int i = 0; i < 4; ++i)
        u[i] = (((u[i] >> 16) | (u[i] << 16)) ^ 0x00008000u);
    return __builtin_bit_cast(bf16x8, u);
}

// ---------------------------------------------------------------------------
// In-place radix-2 DIT FFT, length 4096, bit-reversed input. 256 threads.
// ---------------------------------------------------------------------------
__device__ __forceinline__ void fft4096(float2* buf) {
    for (int half = 1; half < NT; half <<= 1) {
        __syncthreads();
        const float fac = -(float)M_PI / (float)half;
        for (int t = threadIdx.x; t < NT / 2; t += 256) {
            int pos = t & (half - 1);
            int i = 2 * t - pos;
            int j = i + half;
            float sw, cw;
            __sincosf(fac * (float)pos, &sw, &cw);
            float2 u = buf[i], v = buf[j];
            float vr = v.x * cw - v.y * sw;
            float vi = v.x * sw + v.y * cw;
            buf[i] = make_float2(u.x + vr, u.y + vi);
            buf[j] = make_float2(u.x - vr, u.y - vi);
        }
    }
    __syncthreads();
}

// rfft -> Xc (B, C, F) float2, fully coalesced contiguous writes
__global__ __launch_bounds__(256) void fft_fwd_kernel(const float* __restrict__ x_in,
                                                      float2* __restrict__ Xc) {
    __shared__ float2 buf[NT];
    int bc = blockIdx.x;
    const float* xrow = x_in + (size_t)bc * NT;
    for (int i = threadIdx.x; i < NT; i += 256) {
        int r = __brev((unsigned)i) >> 20;
        buf[r] = make_float2(xrow[i], 0.0f);
    }
    fft4096(buf);
    const float inv = 1.0f / 64.0f;
    float2* orow = Xc + (size_t)bc * NF;
    for (int f = threadIdx.x; f < NF; f += 256) {
        float2 v = buf[f];
        orow[f] = make_float2(v.x * inv, v.y * inv);
    }
}

// Transpose Xc (B,C,F) -> Xf (B,F,2C) fp32 and Xb (B,FP,256) bf16 (pad zero)
__global__ __launch_bounds__(256) void xt_kernel(const float2* __restrict__ Xc,
                                                 float2* __restrict__ Xf2,
                                                 bf16* __restrict__ Xb) {
    __shared__ float2 tile[64][65];
    int blk = blockIdx.x;
    int b = blk / 68;
    int t2 = blk % 68;
    int c0 = (t2 / 34) * 64;
    int f0 = (t2 % 34) * 64;
    int t = threadIdx.x;
    int fl = t & 63, cc = t >> 6;
#pragma unroll
    for (int cb = 0; cb < 16; ++cb) {
        int cl = cb * 4 + cc;
        int f = f0 + fl;
        float2 v = make_float2(0.f, 0.f);
        if (f < NF) v = Xc[((size_t)b * NC + c0 + cl) * NF + f];
        tile[fl][cl] = v;
    }
    __syncthreads();
    int chl = t & 63, ww = t >> 6;
#pragma unroll
    for (int wb = 0; wb < 16; ++wb) {
        int fl2 = wb * 4 + ww;
        int f = f0 + fl2;
        float2 v = tile[fl2][chl];
        if (f < NF) Xf2[((size_t)b * NF + f) * 128 + c0 + chl] = v;
        bf16x2 p;
        p[0] = (bf16)v.x; p[1] = (bf16)v.y;
        *(bf16x2*)&Xb[((size_t)b * FP + f) * 256 + 2 * (c0 + chl)] = p;
    }
}

// ---------------------------------------------------------------------------
// Packed weight matrices (bf16):
//  Wk1 (256 x 256): rows -> K1 (Kr,-Ki interleaved)   [K2 derived in-register]
//  Av  (256 x 256): rows -> Vt (Vr,Vi interleaved)
// ---------------------------------------------------------------------------
__global__ __launch_bounds__(256) void wpack_kernel(const float* __restrict__ W_K,
                                                    const float* __restrict__ W_V,
                                                    bf16* __restrict__ Wk1,
                                                    bf16* __restrict__ Av) {
    int idx = blockIdx.x * 256 + threadIdx.x;
    if (idx < 256 * 256) {
        int n = idx >> 8, k = idx & 255;
        int c = k >> 1;
        int j = n >> 1;
        float v = 0.f;
        if (!(n & 1) && !(k & 1)) v = W_K[j * NC + c];
        else if ((n & 1) && (k & 1)) v = -W_K[j * NC + c];
        Wk1[idx] = (bf16)v;
        float v2 = 0.f;
        if (!(n & 1) && !(k & 1)) v2 = W_V[j * NC + c];
        else if ((n & 1) && (k & 1)) v2 = W_V[j * NC + c];
        Av[idx] = (bf16)v2;
    }
}

// K1[(b*FP+g)*256 + n] = sum_k Xb[b,g,k] * Wk1[n,k]
__global__ __launch_bounds__(256, 2) void kvgemm_kernel(const bf16* __restrict__ Xb,
                                                        const bf16* __restrict__ Wk1,
                                                        bf16* __restrict__ K1) {
    __shared__ bf16 As[128][LDP];
    __shared__ bf16 Bs[128][LDP];
    int blk = blockIdx.x;
    int b = blk & 7;
    int t2 = blk >> 3;
    int g0 = (t2 >> 1) * 128;
    int n0 = (t2 & 1) * 128;
    int tid = threadIdx.x;
    int wave = tid >> 6, lane = tid & 63;
    int m = lane & 15, quad = lane >> 4;
    int row_off = (wave & 1) * 64, col_off = (wave >> 1) * 64;

    f32x4 acc[4][4] = {};
    const bf16* Abase = Xb + ((size_t)b * FP + g0) * 256;
    const bf16* Bbase = Wk1 + (size_t)n0 * 256;
    int r0 = tid >> 3, c0 = (tid & 7) * 8;

    for (int kk = 0; kk < 256; kk += 64) {
        __syncthreads();
#pragma unroll
        for (int s = 0; s < 4; ++s) {
            int r = r0 + 32 * s;
            *(bf16x8*)&As[r][c0] = *(const bf16x8*)&Abase[(size_t)r * 256 + kk + c0];
            *(bf16x8*)&Bs[r][c0] = *(const bf16x8*)&Bbase[(size_t)r * 256 + kk + c0];
        }
        __syncthreads();
#pragma unroll
        for (int k2 = 0; k2 < 64; k2 += 32) {
            bf16x8 a[4], bb[4];
            int kq = k2 + quad * 8;
#pragma unroll
            for (int i = 0; i < 4; ++i) a[i] = *(const bf16x8*)&As[row_off + i * 16 + m][kq];
#pragma unroll
            for (int j = 0; j < 4; ++j) bb[j] = *(const bf16x8*)&Bs[col_off + j * 16 + m][kq];
#pragma unroll
            for (int i = 0; i < 4; ++i)
#pragma unroll
                for (int j = 0; j < 4; ++j)
                    acc[i][j] = __builtin_amdgcn_mfma_f32_16x16x32_bf16(a[i], bb[j], acc[i][j], 0, 0, 0);
        }
    }
#pragma unroll
    for (int i = 0; i < 4; ++i)
#pragma unroll
        for (int j = 0; j < 4; ++j)
#pragma unroll
            for (int r = 0; r < 4; ++r) {
                int row = g0 + row_off + i * 16 + quad * 4 + r;
                int col = n0 + col_off + j * 16 + m;
                K1[((size_t)b * FP + row) * 256 + col] = (bf16)acc[i][j][r];
            }
}

// Vt[(b*256+n)*FP + g] = sum_k Av[n,k] * Xb[b,g,k]
__global__ __launch_bounds__(256, 2) void vtgemm_kernel(const bf16* __restrict__ Av,
                                                        const bf16* __restrict__ Xb,
                                                        bf16* __restrict__ Vt) {
    __shared__ bf16 As[128][LDP];
    __shared__ bf16 Bs[128][LDP];
    int blk = blockIdx.x;
    int b = blk & 7;
    int t2 = blk >> 3;
    int g0 = (t2 >> 1) * 128;
    int n0 = (t2 & 1) * 128;
    int tid = threadIdx.x;
    int wave = tid >> 6, lane = tid & 63;
    int m = lane & 15, quad = lane >> 4;
    int row_off = (wave & 1) * 64, col_off = (wave >> 1) * 64;

    f32x4 acc[4][4] = {};
    const bf16* Abase = Av + (size_t)n0 * 256;
    const bf16* Bbase = Xb + ((size_t)b * FP + g0) * 256;
    int r0 = tid >> 3, c0 = (tid & 7) * 8;

    for (int kk = 0; kk < 256; kk += 64) {
        __syncthreads();
#pragma unroll
        for (int s = 0; s < 4; ++s) {
            int r = r0 + 32 * s;
            *(bf16x8*)&As[r][c0] = *(const bf16x8*)&Abase[(size_t)r * 256 + kk + c0];
            *(bf16x8*)&Bs[r][c0] = *(const bf16x8*)&Bbase[(size_t)r * 256 + kk + c0];
        }
        __syncthreads();
#pragma unroll
        for (int k2 = 0; k2 < 64; k2 += 32) {
            bf16x8 a[4], bb[4];
            int kq = k2 + quad * 8;
#pragma unroll
            for (int i = 0; i < 4; ++i) a[i] = *(const bf16x8*)&As[row_off + i * 16 + m][kq];
#pragma unroll
            for (int j = 0; j < 4; ++j) bb[j] = *(const bf16x8*)&Bs[col_off + j * 16 + m][kq];
#pragma unroll
            for (int i = 0; i < 4; ++i)
#pragma unroll
                for (int j = 0; j < 4; ++j)
                    acc[i][j] = __builtin_amdgcn_mfma_f32_16x16x32_bf16(a[i], bb[j], acc[i][j], 0, 0, 0);
        }
    }
#pragma unroll
    for (int i = 0; i < 4; ++i)
#pragma unroll
        for (int j = 0; j < 4; ++j)
#pragma unroll
            for (int r = 0; r < 4; ++r) {
                int row = n0 + row_off + i * 16 + quad * 4 + r;
                int col = g0 + col_off + j * 16 + m;
                Vt[((size_t)b * 256 + row) * FP + col] = (bf16)acc[i][j][r];
            }
}

// DC-bin bias: rfft(const b, ortho) = sqrt(N)*b at f=0 only (re part)
__global__ __launch_bounds__(128) void biasfix_kernel(const float* __restrict__ b_K,
                                                      const float* __restrict__ b_V,
                                                      bf16* __restrict__ K1,
                                                      bf16* __restrict__ Vt) {
    int b = blockIdx.x;
    int j = threadIdx.x;
    float bk = 64.0f * b_K[j], bv = 64.0f * b_V[j];
    size_t o = (size_t)b * FP * 256;
    K1[o + 2 * j] = (bf16)((float)K1[o + 2 * j] + bk);
    size_t ov = ((size_t)b * 256 + 2 * j) * FP;
    Vt[ov] = (bf16)((float)Vt[ov] + bv);
}

__global__ __launch_bounds__(256) void energy_kernel(const float* __restrict__ Xf,
                                                     float* __restrict__ energy) {
    int idx = blockIdx.x * 256 + threadIdx.x;
    if (idx >= NB * NF) return;
    const float4* row = (const float4*)(Xf + (size_t)idx * 2 * NC);
    float e = 0.f;
    for (int i = 0; i < 64; ++i) {
        float4 v = row[i];
        e += v.x * v.x + v.y * v.y + v.z * v.z + v.w * v.w;
    }
    energy[idx] = e;
}

// per-batch median: batch x 9 chunk blocks, float4 LDS rank loop
__global__ __launch_bounds__(256) void median_kernel(const float* __restrict__ energy,
                                                     float* __restrict__ med) {
    int blk = blockIdx.x;
    int b = blk / 9, chunk = blk % 9;
    __shared__ __align__(16) float e[2052];
    for (int i = threadIdx.x; i < 2052; i += 256)
        e[i] = (i < NF) ? energy[b * NF + i] : INFINITY;
    __syncthreads();
    int i = chunk * 256 + threadIdx.x;
    float ei = (i < NF) ? e[i] : 0.f;
    int rank = 0;
#pragma unroll 4
    for (int j4 = 0; j4 < 513; ++j4) {
        float4 v = ((const float4*)e)[j4];
        int j = j4 * 4;
        rank += (v.x < ei) || (v.x == ei && j + 0 < i);
        rank += (v.y < ei) || (v.y == ei && j + 1 < i);
        rank += (v.z < ei) || (v.z == ei && j + 2 < i);
        rank += (v.w < ei) || (v.w == ei && j + 3 < i);
    }
    if (i < NF && rank == 1024) med[b] = ei;
}

__global__ __launch_bounds__(256) void norm_kernel(const float* __restrict__ energy,
                                                   const float* __restrict__ med,
                                                   float* __restrict__ nrm) {
    int idx = blockIdx.x * 256 + threadIdx.x;
    if (idx >= NB * NF) return;
    int b = idx / NF;
    nrm[idx] = energy[idx] / (med[b] + 1e-6f);
}

// Global quantile: 2-D distributed rank selection.
__global__ __launch_bounds__(256) void rankpart_kernel(const float* __restrict__ nrm,
                                                       int* __restrict__ rankpart) {
    const int n = NB * NF;
    int cb = blockIdx.x / 17;
    int chunk = blockIdx.x % 17;
    __shared__ __align__(16) float cdata[1024];
    int base = chunk * 1024;
    for (int t = threadIdx.x; t < 1024; t += 256)
        cdata[t] = (base + t < n) ? nrm[base + t] : INFINITY;
    __syncthreads();
    int i = cb * 256 + threadIdx.x;
    if (i >= n) return;
    float ei = nrm[i];
    int rank = 0;
#pragma unroll 8
    for (int t4 = 0; t4 < 256; ++t4) {
        float4 v = ((const float4*)cdata)[t4];
        int j = base + t4 * 4;
        rank += (v.x < ei) || (v.x == ei && j + 0 < i);
        rank += (v.y < ei) || (v.y == ei && j + 1 < i);
        rank += (v.z < ei) || (v.z == ei && j + 2 < i);
        rank += (v.w < ei) || (v.w == ei && j + 3 < i);
    }
    rankpart[(size_t)i * 17 + chunk] = rank;
}

__global__ __launch_bounds__(256) void rankreduce_kernel(const int* __restrict__ rankpart,
                                                         const float* __restrict__ nrm,
                                                         const float* __restrict__ q,
                                                         float* __restrict__ vk) {
    const int n = NB * NF;
    int i = blockIdx.x * 256 + threadIdx.x;
    if (i >= n) return;
    int rank = 0;
    const int* rp = rankpart + (size_t)i * 17;
#pragma unroll
    for (int c = 0; c < 17; ++c) rank += rp[c];
    double pos = (double)q[0] * (double)(n - 1);
    int k0 = (int)floor(pos);
    int k1 = min(k0 + 1, n - 1);
    if (rank == k0) vk[0] = nrm[i];
    if (rank == k1) vk[1] = nrm[i];
}

__global__ void thresh_kernel(const float* __restrict__ vk,
                              const float* __restrict__ q,
                              float* __restrict__ thr) {
    if (threadIdx.x == 0 && blockIdx.x == 0) {
        const int n = NB * NF;
        double pos = (double)q[0] * (double)(n - 1);
        double k0 = floor(pos);
        double frac = pos - k0;
        thr[0] = (float)((double)vk[0] + ((double)vk[1] - (double)vk[0]) * frac);
    }
}

// ---------------------------------------------------------------------------
// Flash attention: per block 64 f-rows x all g. Online softmax, S never
// materialized. LDS = A(32K) + KV(32K shared: K / V-halves + P) = 64 KB,
// 2 blocks/CU. Wave w owns f-rows w*16..w*16+15, O = 16x256 fp32 in regs.
// ---------------------------------------------------------------------------
__global__ __launch_bounds__(256, 2) void flash_kernel(const bf16* __restrict__ Xb,
                                                       const bf16* __restrict__ K1,
                                                       const bf16* __restrict__ Vt,
                                                       float* __restrict__ Ctx) {
    __shared__ __align__(16) char smem[65536];
    bf16* As = (bf16*)smem;                    // 4 panels x 64x64
    bf16* KV = (bf16*)(smem + 32768);          // 16384 elems (K tile / V halves)
    bf16* Pw = (bf16*)(smem + 32768 + 16384);  // 64 x 72 bf16 (upper half of KV buf)
    int blk = blockIdx.x;
    int b = blk & 7;
    int f0 = (blk >> 3) * 64;
    int tid = threadIdx.x;
    int wave = tid >> 6, lane = tid & 63;
    int m = lane & 15, quad = lane >> 4;
    int lrow = lane >> 3;
    int cswz = (lane & 7) ^ lrow;
    int mk = m & 7;
    const float SCALE = 0.08838834764831845f;  // 1/sqrt(128)

    const bf16* Ab = Xb + ((size_t)b * FP + f0) * 256;
    const bf16* Kb = K1 + (size_t)b * FP * 256;
    const bf16* Vb = Vt + (size_t)b * 256 * FP;

    // stage A once (drained by first in-loop barrier)
#pragma unroll
    for (int p = 0; p < 4; ++p)
#pragma unroll
        for (int t = 0; t < 2; ++t) {
            int r0 = wave * 16 + t * 8;
            async16(Ab + (size_t)(r0 + lrow) * 256 + p * 64 + cswz * 8,
                    As + p * 4096 + r0 * 64);
        }

    float mrow[4] = {-1e30f, -1e30f, -1e30f, -1e30f};
    float lsum[4] = {0.f, 0.f, 0.f, 0.f};
    f32x4 o[16] = {};

    for (int gi = 0; gi < 33; ++gi) {
        int g0 = gi * 64;
        __syncthreads();  // prev-iter KV reads done (and A drain on gi=0)
        // stage K tile (64 g-rows x 256 k) into KV
#pragma unroll
        for (int p = 0; p < 4; ++p)
#pragma unroll
            for (int t = 0; t < 2; ++t) {
                int r0 = wave * 16 + t * 8;
                async16(Kb + (size_t)(g0 + r0 + lrow) * 256 + p * 64 + cswz * 8,
                        KV + p * 4096 + r0 * 64);
            }
        __syncthreads();  // drain K

        // ----- S phase: rows wave*16..+15, cols g0..g0+63 -----
        f32x4 accRe[4] = {};
        f32x4 accIm[4] = {};
#pragma unroll
        for (int ks = 0; ks < 8; ++ks) {
            int p = ks >> 1;
            int pos = (((ks & 1) * 4 + quad) ^ mk) << 3;
            bf16x8 a = *(const bf16x8*)&As[p * 4096 + (wave * 16 + m) * 64 + pos];
#pragma unroll
            for (int j2 = 0; j2 < 4; ++j2) {
                bf16x8 b1 = *(const bf16x8*)&KV[p * 4096 + (j2 * 16 + m) * 64 + pos];
                bf16x8 b2 = derive_b2(b1);
                accRe[j2] = __builtin_amdgcn_mfma_f32_16x16x32_bf16(a, b1, accRe[j2], 0, 0, 0);
                accIm[j2] = __builtin_amdgcn_mfma_f32_16x16x32_bf16(a, b2, accIm[j2], 0, 0, 0);
            }
        }

        // ----- online softmax (per row r: quad*4+r, cols across m-lanes) -----
        float pv[4][4];
        float tmax[4] = {-1e30f, -1e30f, -1e30f, -1e30f};
#pragma unroll
        for (int j2 = 0; j2 < 4; ++j2) {
            int gcol = g0 + j2 * 16 + m;
            bool valid = (gcol <= 2048);
#pragma unroll
            for (int r = 0; r < 4; ++r) {
                float re = accRe[j2][r], im = accIm[j2][r];
                float s = valid ? sqrtf(re * re + im * im) * SCALE : -1e30f;
                pv[j2][r] = s;
                tmax[r] = fmaxf(tmax[r], s);
            }
        }
#pragma unroll
        for (int r = 0; r < 4; ++r) {
            tmax[r] = fmaxf(tmax[r], __shfl_xor(tmax[r], 1));
            tmax[r] = fmaxf(tmax[r], __shfl_xor(tmax[r], 2));
            tmax[r] = fmaxf(tmax[r], __shfl_xor(tmax[r], 4));
            tmax[r] = fmaxf(tmax[r], __shfl_xor(tmax[r], 8));
        }
        float alpha[4], rs[4];
#pragma unroll
        for (int r = 0; r < 4; ++r) {
            float mn = fmaxf(mrow[r], tmax[r]);
            alpha[r] = __expf(mrow[r] - mn);
            mrow[r] = mn;
            rs[r] = 0.f;
        }
#pragma unroll
        for (int j2 = 0; j2 < 4; ++j2)
#pragma unroll
            for (int r = 0; r < 4; ++r) {
                float e = __expf(pv[j2][r] - mrow[r]);
                pv[j2][r] = e;
                rs[r] += e;
            }
#pragma unroll
        for (int r = 0; r < 4; ++r) {
            rs[r] += __shfl_xor(rs[r], 1);
            rs[r] += __shfl_xor(rs[r], 2);
            rs[r] += __shfl_xor(rs[r], 4);
            rs[r] += __shfl_xor(rs[r], 8);
            lsum[r] = lsum[r] * alpha[r] + rs[r];
        }
#pragma unroll
        for (int j = 0; j < 16; ++j)
#pragma unroll
            for (int r = 0; r < 4; ++r) o[j][r] *= alpha[r];

        __syncthreads();  // all waves done reading K
        // stage V half 1 (n 0..127) + write P (C-layout -> row-major LDS)
#pragma unroll
        for (int t = 0; t < 4; ++t) {
            int n0 = wave * 32 + t * 8;
            async16(Vb + (size_t)(n0 + lrow) * FP + g0 + cswz * 8, KV + n0 * 64);
        }
#pragma unroll
        for (int j2 = 0; j2 < 4; ++j2)
#pragma unroll
            for (int r = 0; r < 4; ++r)
                Pw[(wave * 16 + quad * 4 + r) * 72 + j2 * 16 + m] = (bf16)pv[j2][r];
        __syncthreads();  // drain V1 + P visible

        bf16x8 pa[2];
#pragma unroll
        for (int ks2 = 0; ks2 < 2; ++ks2) {
            pa[ks2] = *(const bf16x8*)&Pw[(wave * 16 + m) * 72 + ks2 * 32 + quad * 8];
            int pos = ((ks2 * 4 + quad) ^ mk) << 3;
#pragma unroll
            for (int j = 0; j < 8; ++j) {
                bf16x8 vb = *(const bf16x8*)&KV[(j * 16 + m) * 64 + pos];
                o[j] = __builtin_amdgcn_mfma_f32_16x16x32_bf16(pa[ks2], vb, o[j], 0, 0, 0);
            }
        }
        __syncthreads();  // V1 reads done
        // stage V half 2 (n 128..255)
#pragma unroll
        for (int t = 0; t < 4; ++t) {
            int n0 = 128 + wave * 32 + t * 8;
            async16(Vb + (size_t)(n0 + lrow) * FP + g0 + cswz * 8, KV + (n0 - 128) * 64);
        }
        __syncthreads();  // drain V2
#pragma unroll
        for (int ks2 = 0; ks2 < 2; ++ks2) {
            int pos = ((ks2 * 4 + quad) ^ mk) << 3;
#pragma unroll
            for (int j = 8; j < 16; ++j) {
                bf16x8 vb = *(const bf16x8*)&KV[((j - 8) * 16 + m) * 64 + pos];
                o[j] = __builtin_amdgcn_mfma_f32_16x16x32_bf16(pa[ks2], vb, o[j], 0, 0, 0);
            }
        }
    }

    // epilogue: O / l, write Ctx
    float inv[4];
#pragma unroll
    for (int r = 0; r < 4; ++r) inv[r] = 1.f / lsum[r];
#pragma unroll
    for (int j = 0; j < 16; ++j)
#pragma unroll
        for (int r = 0; r < 4; ++r) {
            int row = f0 + wave * 16 + quad * 4 + r;
            if (row < NF)
                Ctx[((size_t)b * NF + row) * 256 + j * 16 + m] = o[j][r] * inv[r];
        }
}

// Fused hifreq + transpose: Ctxt[b, ch, f] = Ctx[b,f,ch] + mask*(X*w_hi)
__global__ __launch_bounds__(256) void ctxt_kernel(const float2* __restrict__ Ctx2,
                                                   const float2* __restrict__ Xf2,
                                                   const float* __restrict__ nrm,
                                                   const float* __restrict__ thr,
                                                   const float* __restrict__ w_high,
                                                   float* __restrict__ Ctxt) {
    __shared__ float2 tile[64][33];
    int blk = blockIdx.x;
    int b = blk / 132;
    int t2 = blk % 132;
    int cp0 = (t2 / 33) * 32;
    int f0 = (t2 % 33) * 64;
    int t = threadIdx.x;
    float thrv = thr[0];
    int cpl = t & 31, rr = t >> 5;
#pragma unroll
    for (int rb = 0; rb < 8; ++rb) {
        int fl = rb * 8 + rr;
        int f = f0 + fl;
        float2 v = make_float2(0.f, 0.f);
        if (f < NF) {
            size_t idx = ((size_t)b * NF + f) * 128 + cp0 + cpl;
            v = Ctx2[idx];
            if (nrm[b * NF + f] > thrv) {
                float2 x = Xf2[idx];
                int c = cp0 + cpl;
                float wr = w_high[2 * c], wi = w_high[2 * c + 1];
                v.x += x.x * wr - x.y * wi;
                v.y += x.x * wi + x.y * wr;
            }
        }
        tile[fl][cpl] = v;
    }
    __syncthreads();
    int fl = t & 63, ww = t >> 6;
#pragma unroll
    for (int wb = 0; wb < 16; ++wb) {
        int chl = wb * 4 + ww;
        int f = f0 + fl;
        if (f < NF) {
            float2 v = tile[fl][chl >> 1];
            Ctxt[((size_t)b * 256 + 2 * cp0 + chl) * NF + f] = (chl & 1) ? v.y : v.x;
        }
    }
}

// irfft (ortho) reading contiguous Ctxt rows
__global__ __launch_bounds__(256) void fft_inv_kernel(const float* __restrict__ Ctxt,
                                                      float* __restrict__ out) {
    __shared__ float2 buf[NT];
    int bc = blockIdx.x, b = bc >> 7, c = bc & 127;
    const float* base = Ctxt + ((size_t)b * 256 + 2 * c) * NF;
    const float* basei = base + NF;
    for (int f = threadIdx.x; f < NT; f += 256) {
        float re, im;
        if (f <= NT / 2) {
            re = base[f];
            im = -basei[f];
        } else {
            int g = NT - f;
            re = base[g];
            im = basei[g];
        }
        int r = __brev((unsigned)f) >> 20;
        buf[r] = make_float2(re, im);
    }
    fft4096(buf);
    float* orow = out + (size_t)bc * NT;
    const float inv = 1.0f / 64.0f;
    for (int n = threadIdx.x; n < NT; n += 256) orow[n] = buf[n].x * inv;
}

extern "C" void kernel_launch(void* const* d_in, const int* in_sizes, int n_in,
                              void* d_out, int out_size, void* d_ws, size_t ws_size,
                              hipStream_t stream) {
    const float* x_in = (const float*)d_in[0];
    const float* W_K = (const float*)d_in[1];
    const float* b_K = (const float*)d_in[2];
    const float* W_V = (const float*)d_in[3];
    const float* b_V = (const float*)d_in[4];
    const float* w_high = (const float*)d_in[5];
    const float* qpar = (const float*)d_in[6];
    float* out = (float*)d_out;

    char* w = (char*)d_ws;
    const size_t SPECB = (size_t)NB * NF * 256 * 4;       // 16.8 MB
    float* Xf = (float*)w;            w += SPECB;
    float* Ctx = (float*)w;           w += SPECB;
    float* energy = (float*)w;        w += (size_t)NB * NF * 4;
    float* med = (float*)w;           w += 64;
    float* nrm = (float*)w;           w += (size_t)NB * NF * 4;
    float* vk = (float*)w;            w += 64;
    float* thr = (float*)w;           w += 64;
    w = (char*)(((uintptr_t)w + 255) & ~(uintptr_t)255);
    int* rankpart = (int*)w;          w += (size_t)16640 * 17 * 4;      // 1.1 MB
    w = (char*)(((uintptr_t)w + 255) & ~(uintptr_t)255);
    bf16* Xb = (bf16*)w;              w += (size_t)NB * FP * 256 * 2;   // 8.9 MB
    bf16* K1 = (bf16*)w;              w += (size_t)NB * FP * 256 * 2;   // 8.9 MB
    bf16* Vt = (bf16*)w;              w += (size_t)NB * 256 * FP * 2;   // 8.9 MB
    bf16* Wk1 = (bf16*)w;             w += (size_t)256 * 256 * 2;
    bf16* Av = (bf16*)w;              w += (size_t)256 * 256 * 2;
    // Aliases (lifetimes disjoint):
    float2* Xc = (float2*)Ctx;    // fft_fwd -> xt only; Ctx written by flash later
    float* Ctxt = (float*)Xb;     // spans Xb+K1 (both dead after flash)

    fft_fwd_kernel<<<NB * NC, 256, 0, stream>>>(x_in, Xc);
    xt_kernel<<<NB * 2 * 34, 256, 0, stream>>>(Xc, (float2*)Xf, Xb);
    wpack_kernel<<<256, 256, 0, stream>>>(W_K, W_V, Wk1, Av);
    kvgemm_kernel<<<NB * 17 * 2, 256, 0, stream>>>(Xb, Wk1, K1);
    vtgemm_kernel<<<NB * 17 * 2, 256, 0, stream>>>(Av, Xb, Vt);
    biasfix_kernel<<<NB, 128, 0, stream>>>(b_K, b_V, K1, Vt);
    energy_kernel<<<(NB * NF + 255) / 256, 256, 0, stream>>>(Xf, energy);
    median_kernel<<<NB * 9, 256, 0, stream>>>(energy, med);
    norm_kernel<<<(NB * NF + 255) / 256, 256, 0, stream>>>(energy, med, nrm);
    rankpart_kernel<<<65 * 17, 256, 0, stream>>>(nrm, rankpart);
    rankreduce_kernel<<<65, 256, 0, stream>>>(rankpart, nrm, qpar, vk);
    thresh_kernel<<<1, 64, 0, stream>>>(vk, qpar, thr);
    flash_kernel<<<NB * 33, 256, 0, stream>>>(Xb, K1, Vt, Ctx);
    ctxt_kernel<<<NB * 4 * 33, 256, 0, stream>>>((const float2*)Ctx, (const float2*)Xf,
                                                 nrm, thr, w_high, Ctxt);
    fft_inv_kernel<<<NB * NC, 256, 0, stream>>>(Ctxt, out);
}